// Round 16
// baseline (253.298 us; speedup 1.0000x reference)
//
#include <hip/hip_runtime.h>
#include <hip/hip_fp16.h>

// GCN encoder: 3x GCNConv (+self-loops, sym deg^-1/2 norm) + ELU + mean-pool.
// N=50000, E=800000, IN=128, HID=64, ZDIM=64, G=64. f32 in/out.
// R4/R5 lessons: no big per-lane arrays; bound unroll of LDS-heavy loops.
// R7: CSR gather. R8: parallel scan. R9: fp16 gathered operands.
// R10: fill unmerged. R11: atomic-free fill. R12: two-stage pool.
// R13: gather2+pool fused. R14: lane-vectorized gathers (not instr-bound).
// R15: 8 rows in flight -> 252us; top-5 all harness poison fills now.
// R16: 16 rows in flight (csr idx are wave-uniform -> SGPRs; 16 float2 rows
//     = ~40 VGPR, still 32 waves/CU -> outstanding doubles). Discriminating
//     experiment: neutral => random-gather L3 floor reached.

#define IN_DIM 128
#define HID 64
#define ZDIM 64
#define N_GRAPHS 64
#define SCAN_B 1024
#define POOL2_WAVES 8192   // 32 waves/CU x 256 CU

__device__ __forceinline__ float elu1(float x) {
    return x > 0.f ? x : expm1f(x);
}

// rank[e] = within-dst arrival index; kc[d] ends as deg(d).
__global__ void k_count(const int* __restrict__ dst, int* __restrict__ kc,
                        int* __restrict__ rank, int E) {
    int e = blockIdx.x * blockDim.x + threadIdx.x;
    if (e < E) rank[e] = atomicAdd(&kc[dst[e]], 1);
}

// S1: per-block sum of kc -> bsum[blk]
__global__ __launch_bounds__(SCAN_B) void k_scan1(const int* __restrict__ kc,
                                                  int* __restrict__ bsum, int n) {
    __shared__ int wpart[16];
    int tid = threadIdx.x, lane = tid & 63, w = tid >> 6;
    int i = blockIdx.x * SCAN_B + tid;
    int v = (i < n) ? kc[i] : 0;
#pragma unroll
    for (int d = 1; d < 64; d <<= 1) v += __shfl_xor(v, d, 64);
    if (lane == 0) wpart[w] = v;
    __syncthreads();
    if (tid < 16) {
        int t = wpart[tid];
#pragma unroll
        for (int d = 1; d < 16; d <<= 1) t += __shfl_xor(t, d, 64);
        if (tid == 0) bsum[blockIdx.x] = t;
    }
}

// S3: each block re-scans bsum in-register (nb<=64) for its base, then
// offs[i+1] = inclusive prefix, dinv[i] = 1/sqrt(1+kc[i]).
__global__ __launch_bounds__(SCAN_B) void k_scan3(const int* __restrict__ kc,
                                                  const int* __restrict__ bsum,
                                                  int* __restrict__ offs,
                                                  float* __restrict__ dinv,
                                                  int n, int nb) {
    __shared__ int wsum[16];
    __shared__ int sbase;
    int tid = threadIdx.x, lane = tid & 63, w = tid >> 6;
    if (tid < 64) {  // wave 0: exclusive prefix of bsum at blockIdx.x
        int v = (tid < nb) ? bsum[tid] : 0;
        int s = v;
#pragma unroll
        for (int d = 1; d < 64; d <<= 1) {
            int u = __shfl_up(s, d, 64);
            if (tid >= d) s += u;
        }
        if (tid == blockIdx.x) sbase = s - v;
    }
    int i = blockIdx.x * SCAN_B + tid;
    int v = (i < n) ? kc[i] : 0;
    int s = v;
#pragma unroll
    for (int d = 1; d < 64; d <<= 1) {
        int u = __shfl_up(s, d, 64);
        if (lane >= d) s += u;
    }
    if (lane == 63) wsum[w] = s;
    __syncthreads();
    if (tid < 16) {
        int t = wsum[tid];
#pragma unroll
        for (int d = 1; d < 16; d <<= 1) {
            int u = __shfl_up(t, d, 64);
            if (tid >= d) t += u;
        }
        wsum[tid] = t;
    }
    __syncthreads();
    int base = sbase + ((w == 0) ? 0 : wsum[w - 1]);
    if (i < n) {
        offs[i + 1] = base + s;
        dinv[i] = 1.0f / sqrtf(1.0f + (float)v);
        if (i == 0) offs[0] = 0;
    }
}

// Atomic-free fill: unique slot per edge (offs[dst] + rank).
__global__ void k_fill(const int* __restrict__ src, const int* __restrict__ dst,
                       const int* __restrict__ rank, const int* __restrict__ offs,
                       int* __restrict__ csr, int E) {
    int e = blockIdx.x * blockDim.x + threadIdx.x;
    if (e < E) csr[offs[dst[e]] + rank[e]] = src[e];
}

// ts1h[64-tile] = fp16((x_tile[64x128] @ W[128x64]) * dinv).
__global__ __launch_bounds__(256) void k_mm1(const float* __restrict__ x,
                                             const float* __restrict__ W,
                                             const float* __restrict__ dinv,
                                             __half* __restrict__ ts1h, int n) {
    __shared__ float xs[64 * 68];
    __shared__ float ws[64 * 68];
    const int tid = threadIdx.x;
    const int m0 = blockIdx.x * 64;
    const int j = tid & 15;
    const int i = tid >> 4;

    const float4* x4 = (const float4*)x;
    const float4* W4 = (const float4*)W;

    float4 acc[4];
#pragma unroll
    for (int r = 0; r < 4; ++r) acc[r] = make_float4(0.f, 0.f, 0.f, 0.f);

    for (int kk = 0; kk < IN_DIM; kk += 64) {
        __syncthreads();
        for (int idx = tid; idx < 64 * 16; idx += 256) {
            int row = idx >> 4, c4 = idx & 15;
            float4 v = make_float4(0.f, 0.f, 0.f, 0.f);
            if (m0 + row < n) v = x4[(size_t)(m0 + row) * 32 + (kk >> 2) + c4];
            *(float4*)&xs[row * 68 + 4 * c4] = v;
            *(float4*)&ws[row * 68 + 4 * c4] = W4[(size_t)(kk + row) * 16 + c4];
        }
        __syncthreads();
#pragma unroll 1   // dynamic: bounds LDS-read hoisting / VGPR pressure (R5 lesson)
        for (int k4 = 0; k4 < 16; ++k4) {
            float4 a[4];
#pragma unroll
            for (int r = 0; r < 4; ++r)
                a[r] = *(const float4*)&xs[(4 * i + r) * 68 + 4 * k4];
#pragma unroll
            for (int kc = 0; kc < 4; ++kc) {
                float4 bv = *(const float4*)&ws[(4 * k4 + kc) * 68 + 4 * j];
#pragma unroll
                for (int r = 0; r < 4; ++r) {
                    float av = (&a[r].x)[kc];
                    acc[r].x = fmaf(av, bv.x, acc[r].x);
                    acc[r].y = fmaf(av, bv.y, acc[r].y);
                    acc[r].z = fmaf(av, bv.z, acc[r].z);
                    acc[r].w = fmaf(av, bv.w, acc[r].w);
                }
            }
        }
    }

#pragma unroll
    for (int r = 0; r < 4; ++r) {
        int row = m0 + 4 * i + r;
        if (row < n) {
            float di = dinv[row];
            float4 tv = acc[r];
            __half2* p = (__half2*)&ts1h[(size_t)row * HID + 4 * j];
            p[0] = __floats2half2_rn(tv.x * di, tv.y * di);
            p[1] = __floats2half2_rn(tv.z * di, tv.w * di);
        }
    }
}

// agg1[i] = dinv[i] * (ts[i] + sum_{s in csr} ts[s]); fp16 rows, f32 accum.
// Half-wave split (even/odd CSR slots), 8 slots per half in flight
// (16 rows/wave), shfl_xor(32) combine.
__global__ __launch_bounds__(256) void k_gather_h(const int* __restrict__ off,
                                                  const int* __restrict__ csr,
                                                  const float* __restrict__ dinv,
                                                  const __half* __restrict__ ts,
                                                  float* __restrict__ out, int n) {
    int node = blockIdx.x * 4 + (threadIdx.x >> 6);
    if (node >= n) return;
    int lane = threadIdx.x & 63;
    int half = lane >> 5, l2 = lane & 31;
    int s0 = off[node], s1 = off[node + 1];
    float2 acc = make_float2(0.f, 0.f);
    int k = s0 + half;
    for (; k + 14 < s1; k += 16) {  // slots k, k+2, ..., k+14 (this half)
        int i0 = csr[k],      i1 = csr[k + 2],  i2 = csr[k + 4],  i3 = csr[k + 6];
        int i4 = csr[k + 8],  i5 = csr[k + 10], i6 = csr[k + 12], i7 = csr[k + 14];
        float2 f0 = __half22float2(*(const __half2*)&ts[(size_t)i0 * 64 + 2 * l2]);
        float2 f1 = __half22float2(*(const __half2*)&ts[(size_t)i1 * 64 + 2 * l2]);
        float2 f2 = __half22float2(*(const __half2*)&ts[(size_t)i2 * 64 + 2 * l2]);
        float2 f3 = __half22float2(*(const __half2*)&ts[(size_t)i3 * 64 + 2 * l2]);
        float2 f4 = __half22float2(*(const __half2*)&ts[(size_t)i4 * 64 + 2 * l2]);
        float2 f5 = __half22float2(*(const __half2*)&ts[(size_t)i5 * 64 + 2 * l2]);
        float2 f6 = __half22float2(*(const __half2*)&ts[(size_t)i6 * 64 + 2 * l2]);
        float2 f7 = __half22float2(*(const __half2*)&ts[(size_t)i7 * 64 + 2 * l2]);
        acc.x += ((f0.x + f1.x) + (f2.x + f3.x)) + ((f4.x + f5.x) + (f6.x + f7.x));
        acc.y += ((f0.y + f1.y) + (f2.y + f3.y)) + ((f4.y + f5.y) + (f6.y + f7.y));
    }
    for (; k + 6 < s1; k += 8) {
        int a = csr[k], b = csr[k + 2], c = csr[k + 4], d = csr[k + 6];
        float2 fa = __half22float2(*(const __half2*)&ts[(size_t)a * 64 + 2 * l2]);
        float2 fb = __half22float2(*(const __half2*)&ts[(size_t)b * 64 + 2 * l2]);
        float2 fc = __half22float2(*(const __half2*)&ts[(size_t)c * 64 + 2 * l2]);
        float2 fd = __half22float2(*(const __half2*)&ts[(size_t)d * 64 + 2 * l2]);
        acc.x += (fa.x + fb.x) + (fc.x + fd.x);
        acc.y += (fa.y + fb.y) + (fc.y + fd.y);
    }
    for (; k < s1; k += 2) {
        int a = csr[k];
        float2 fa = __half22float2(*(const __half2*)&ts[(size_t)a * 64 + 2 * l2]);
        acc.x += fa.x;
        acc.y += fa.y;
    }
    acc.x += __shfl_xor(acc.x, 32, 64);
    acc.y += __shfl_xor(acc.y, 32, 64);
    if (half == 0) {
        float2 self = __half22float2(*(const __half2*)&ts[(size_t)node * 64 + 2 * l2]);
        float di = dinv[node];
        float2 o = make_float2((acc.x + self.x) * di, (acc.y + self.y) * di);
        *(float2*)&out[(size_t)node * 64 + 2 * l2] = o;
    }
}

// h = elu(agg1 + b1) (once per element at staging, f32);
// CDh[node][0..63] = fp16((h@Wmu)*dinv), CDh[node][64..127] = fp16((h@Wsig)*dinv).
__global__ __launch_bounds__(256) void k_mm23(const float* __restrict__ agg1,
                                              const float* __restrict__ b1,
                                              const float* __restrict__ Wmu,
                                              const float* __restrict__ Wsig,
                                              const float* __restrict__ dinv,
                                              __half* __restrict__ CDh, int n) {
    __shared__ float hs[64 * 68];
    __shared__ float wc[64 * 132];  // [k][0..63]=Wmu, [k][64..127]=Wsig
    const int tid = threadIdx.x;
    const int m0 = blockIdx.x * 64;
    const int j = tid & 15;
    const int i = tid >> 4;

    const float4* h4 = (const float4*)agg1;
    const float4* b14 = (const float4*)b1;
    const float4* Wm4 = (const float4*)Wmu;
    const float4* Ws4 = (const float4*)Wsig;
    for (int idx = tid; idx < 64 * 16; idx += 256) {
        int row = idx >> 4, c4 = idx & 15;
        float4 v = make_float4(0.f, 0.f, 0.f, 0.f);
        if (m0 + row < n) {
            float4 hv = h4[(size_t)(m0 + row) * 16 + c4];
            float4 bb = b14[c4];
            v.x = elu1(hv.x + bb.x);
            v.y = elu1(hv.y + bb.y);
            v.z = elu1(hv.z + bb.z);
            v.w = elu1(hv.w + bb.w);
        }
        *(float4*)&hs[row * 68 + 4 * c4] = v;
        *(float4*)&wc[row * 132 + 4 * c4] = Wm4[(size_t)row * 16 + c4];
        *(float4*)&wc[row * 132 + 64 + 4 * c4] = Ws4[(size_t)row * 16 + c4];
    }
    __syncthreads();

    float4 accm[4], accs[4];
#pragma unroll
    for (int r = 0; r < 4; ++r) {
        accm[r] = make_float4(0.f, 0.f, 0.f, 0.f);
        accs[r] = make_float4(0.f, 0.f, 0.f, 0.f);
    }

#pragma unroll 1   // dynamic: bounds LDS-read hoisting / VGPR pressure (R5 lesson)
    for (int k4 = 0; k4 < 16; ++k4) {
        float4 a[4];
#pragma unroll
        for (int r = 0; r < 4; ++r)
            a[r] = *(const float4*)&hs[(4 * i + r) * 68 + 4 * k4];
#pragma unroll
        for (int kc = 0; kc < 4; ++kc) {
            float4 bm = *(const float4*)&wc[(4 * k4 + kc) * 132 + 4 * j];
            float4 bs = *(const float4*)&wc[(4 * k4 + kc) * 132 + 64 + 4 * j];
#pragma unroll
            for (int r = 0; r < 4; ++r) {
                float av = (&a[r].x)[kc];
                accm[r].x = fmaf(av, bm.x, accm[r].x);
                accm[r].y = fmaf(av, bm.y, accm[r].y);
                accm[r].z = fmaf(av, bm.z, accm[r].z);
                accm[r].w = fmaf(av, bm.w, accm[r].w);
                accs[r].x = fmaf(av, bs.x, accs[r].x);
                accs[r].y = fmaf(av, bs.y, accs[r].y);
                accs[r].z = fmaf(av, bs.z, accs[r].z);
                accs[r].w = fmaf(av, bs.w, accs[r].w);
            }
        }
    }

#pragma unroll
    for (int r = 0; r < 4; ++r) {
        int row = m0 + 4 * i + r;
        if (row < n) {
            float di = dinv[row];
            float4 m = accm[r], s = accs[r];
            __half2* pm = (__half2*)&CDh[(size_t)row * 128 + 4 * j];
            pm[0] = __floats2half2_rn(m.x * di, m.y * di);
            pm[1] = __floats2half2_rn(m.z * di, m.w * di);
            __half2* ps = (__half2*)&CDh[(size_t)row * 128 + 64 + 4 * j];
            ps[0] = __floats2half2_rn(s.x * di, s.y * di);
            ps[1] = __floats2half2_rn(s.z * di, s.w * di);
        }
    }
}

// Fused mu/sig gather + pool stage-1. Lane = dim-pair (one half2 load covers
// the 256B row). 16 rows in flight per wave (idx in SGPRs, ~40 VGPR ->
// still 32 waves/CU). Span waves, boundary-flush atomics (2/lane).
__global__ __launch_bounds__(256) void k_gather2_pool(const int* __restrict__ offs,
                                                      const int* __restrict__ csr,
                                                      const float* __restrict__ dinv,
                                                      const __half* __restrict__ CD,
                                                      const float* __restrict__ bmu,
                                                      const float* __restrict__ bsig,
                                                      const int* __restrict__ batch,
                                                      float* __restrict__ sums, int n) {
    int lane = threadIdx.x & 63;
    int half = lane >> 5, l2 = lane & 31;
    int wid = (blockIdx.x * 256 + threadIdx.x) >> 6;
    int span = (n + POOL2_WAVES - 1) / POOL2_WAVES;
    int s = wid * span;
    if (s >= n) return;
    int e = min(n, s + span);
    const float2* bb = half ? (const float2*)bsig : (const float2*)bmu;
    float2 bv = bb[l2];
    float* sbase = sums + (half ? 4096 : 0);
    float2 pm = make_float2(0.f, 0.f);
    int g = batch[s];
    int o0 = offs[s];
    for (int node = s; node < e; ++node) {
        int o1 = offs[node + 1];
        float2 am = __half22float2(*(const __half2*)&CD[(size_t)node * 128 + 2 * lane]);
        int k = o0;
        for (; k + 16 <= o1; k += 16) {  // 16 rows in flight
            int a0 = csr[k],      a1 = csr[k + 1],  a2 = csr[k + 2],  a3 = csr[k + 3];
            int a4 = csr[k + 4],  a5 = csr[k + 5],  a6 = csr[k + 6],  a7 = csr[k + 7];
            int a8 = csr[k + 8],  a9 = csr[k + 9],  aa = csr[k + 10], ab = csr[k + 11];
            int ac = csr[k + 12], ad = csr[k + 13], ae = csr[k + 14], af = csr[k + 15];
            float2 f0 = __half22float2(*(const __half2*)&CD[(size_t)a0 * 128 + 2 * lane]);
            float2 f1 = __half22float2(*(const __half2*)&CD[(size_t)a1 * 128 + 2 * lane]);
            float2 f2 = __half22float2(*(const __half2*)&CD[(size_t)a2 * 128 + 2 * lane]);
            float2 f3 = __half22float2(*(const __half2*)&CD[(size_t)a3 * 128 + 2 * lane]);
            float2 f4 = __half22float2(*(const __half2*)&CD[(size_t)a4 * 128 + 2 * lane]);
            float2 f5 = __half22float2(*(const __half2*)&CD[(size_t)a5 * 128 + 2 * lane]);
            float2 f6 = __half22float2(*(const __half2*)&CD[(size_t)a6 * 128 + 2 * lane]);
            float2 f7 = __half22float2(*(const __half2*)&CD[(size_t)a7 * 128 + 2 * lane]);
            float2 f8 = __half22float2(*(const __half2*)&CD[(size_t)a8 * 128 + 2 * lane]);
            float2 f9 = __half22float2(*(const __half2*)&CD[(size_t)a9 * 128 + 2 * lane]);
            float2 fa = __half22float2(*(const __half2*)&CD[(size_t)aa * 128 + 2 * lane]);
            float2 fb = __half22float2(*(const __half2*)&CD[(size_t)ab * 128 + 2 * lane]);
            float2 fc = __half22float2(*(const __half2*)&CD[(size_t)ac * 128 + 2 * lane]);
            float2 fd = __half22float2(*(const __half2*)&CD[(size_t)ad * 128 + 2 * lane]);
            float2 fe = __half22float2(*(const __half2*)&CD[(size_t)ae * 128 + 2 * lane]);
            float2 ff = __half22float2(*(const __half2*)&CD[(size_t)af * 128 + 2 * lane]);
            am.x += (((f0.x + f1.x) + (f2.x + f3.x)) + ((f4.x + f5.x) + (f6.x + f7.x)))
                  + (((f8.x + f9.x) + (fa.x + fb.x)) + ((fc.x + fd.x) + (fe.x + ff.x)));
            am.y += (((f0.y + f1.y) + (f2.y + f3.y)) + ((f4.y + f5.y) + (f6.y + f7.y)))
                  + (((f8.y + f9.y) + (fa.y + fb.y)) + ((fc.y + fd.y) + (fe.y + ff.y)));
        }
        for (; k + 4 <= o1; k += 4) {
            int a = csr[k], b = csr[k + 1], c = csr[k + 2], d = csr[k + 3];
            float2 fa = __half22float2(*(const __half2*)&CD[(size_t)a * 128 + 2 * lane]);
            float2 fb = __half22float2(*(const __half2*)&CD[(size_t)b * 128 + 2 * lane]);
            float2 fc = __half22float2(*(const __half2*)&CD[(size_t)c * 128 + 2 * lane]);
            float2 fd = __half22float2(*(const __half2*)&CD[(size_t)d * 128 + 2 * lane]);
            am.x += (fa.x + fb.x) + (fc.x + fd.x);
            am.y += (fa.y + fb.y) + (fc.y + fd.y);
        }
        for (; k < o1; ++k) {
            int a = csr[k];
            float2 fa = __half22float2(*(const __half2*)&CD[(size_t)a * 128 + 2 * lane]);
            am.x += fa.x;
            am.y += fa.y;
        }
        o0 = o1;
        float di = dinv[node];
        int gn = batch[node];  // wave-uniform broadcast
        if (gn != g) {
            atomicAdd(&sbase[g * 64 + 2 * l2], pm.x);
            atomicAdd(&sbase[g * 64 + 2 * l2 + 1], pm.y);
            pm = make_float2(0.f, 0.f);
            g = gn;
        }
        pm.x += elu1(am.x * di + bv.x);
        pm.y += elu1(am.y * di + bv.y);
    }
    atomicAdd(&sbase[g * 64 + 2 * l2], pm.x);
    atomicAdd(&sbase[g * 64 + 2 * l2 + 1], pm.y);
}

// Pool stage 2: one thread per output element; cnt via binary search.
__global__ void k_pool_final(const float* __restrict__ sums,
                             const int* __restrict__ batch,
                             float* __restrict__ out, int n) {
    int i = blockIdx.x * blockDim.x + threadIdx.x;
    if (i >= 2 * N_GRAPHS * ZDIM) return;
    int g = (i >> 6) & 63;
    int lo = 0, hi = n;
    while (lo < hi) { int m = (lo + hi) >> 1; if (batch[m] < g) lo = m + 1; else hi = m; }
    int s = lo;
    lo = s; hi = n;
    while (lo < hi) { int m = (lo + hi) >> 1; if (batch[m] < g + 1) lo = m + 1; else hi = m; }
    float c = fmaxf((float)(lo - s), 1.0f);
    out[i] = sums[i] / c;
}

extern "C" void kernel_launch(void* const* d_in, const int* in_sizes, int n_in,
                              void* d_out, int out_size, void* d_ws, size_t ws_size,
                              hipStream_t stream) {
    const float* x    = (const float*)d_in[0];
    const int*   ei   = (const int*)d_in[1];
    const int*   batch= (const int*)d_in[2];
    // d_in[3] = num_graphs (scalar, known 64)
    const float* W1   = (const float*)d_in[4];
    const float* b1   = (const float*)d_in[5];
    const float* Wmu  = (const float*)d_in[6];
    const float* bmu  = (const float*)d_in[7];
    const float* Wsig = (const float*)d_in[8];
    const float* bsig = (const float*)d_in[9];
    float* out = (float*)d_out;

    const int n = in_sizes[0] / IN_DIM;   // 50000
    const int E = in_sizes[1] / 2;        // 800000
    const int* src = ei;
    const int* dst = ei + E;
    const int NSB = (n + SCAN_B - 1) / SCAN_B;  // scan blocks (49)

    float* ws = (float*)d_ws;
    size_t off_w = 0;
    int*   kc   = (int*)(ws + off_w); off_w += 50048;
    float* sums = ws + off_w; off_w += 8192;   // contiguous with kc: one memset
    float* dinv = ws + off_w; off_w += 50048;
    int*   offs = (int*)(ws + off_w); off_w += 50056;
    int*   bsum = (int*)(ws + off_w); off_w += 64;
    int*   rank = (int*)(ws + off_w); off_w += 800000;
    int*   csr  = (int*)(ws + off_w); off_w += 800000;
    off_w = (off_w + 15) & ~(size_t)15;
    const size_t BIG = (size_t)n * 64;
    float*  A    = ws + off_w; off_w += BIG;                 // agg1 (f32)
    __half* ts1h = (__half*)(ws + off_w); off_w += BIG / 2;  // fp16 ts1
    __half* CDh  = (__half*)(ws + off_w); off_w += BIG;      // fp16 mu|sig

    const int gE  = (E + 255) / 256;
    const int gNW = (n + 3) / 4;      // one wave per node
    const int NB  = (n + 63) / 64;    // 64-node GEMM tiles

    // CSR build + normalization (kc+sums zeroed in ONE contiguous memset)
    hipMemsetAsync(kc, 0, (50048 + 8192) * sizeof(int), stream);
    k_count<<<gE, 256, 0, stream>>>(dst, kc, rank, E);
    k_scan1<<<NSB, SCAN_B, 0, stream>>>(kc, bsum, n);
    k_scan3<<<NSB, SCAN_B, 0, stream>>>(kc, bsum, offs, dinv, n, NSB);
    k_fill<<<gE, 256, 0, stream>>>(src, dst, rank, offs, csr, E);

    // layer 1: ts1h = fp16((x@W1)*dinv); A = agg1 (f32)
    k_mm1<<<NB, 256, 0, stream>>>(x, W1, dinv, ts1h, n);
    k_gather_h<<<gNW, 256, 0, stream>>>(offs, csr, dinv, ts1h, A, n);

    // layers 2/3: h = elu(A + b1); CDh = fp16 interleaved (h@Wmu|h@Wsig)*dinv
    k_mm23<<<NB, 256, 0, stream>>>(A, b1, Wmu, Wsig, dinv, CDh, n);

    // fused mu/sig gather + pool stage-1 (span waves, boundary-flush atomics)
    k_gather2_pool<<<POOL2_WAVES / 4, 256, 0, stream>>>(offs, csr, dinv, CDh,
                                                        bmu, bsig, batch, sums, n);
    k_pool_final<<<(2 * N_GRAPHS * ZDIM + 255) / 256, 256, 0, stream>>>(sums, batch, out, n);
}